// Round 4
// baseline (55.846 us; speedup 1.0000x reference)
//
#include <hip/hip_runtime.h>

#define N_W   8192
#define N_E   32
#define N_NUC 8
#define D_H   32
#define NTAB  4096
#define TAB_INVH 256.0f    // table step = 1/256, range [0, 16)
#define TAB_H    (1.0f/256.0f)
#define WPB   4            // walkers per block (2 wave-pairs x 2 walkers)

__device__ __forceinline__ float fast_rcp(float x) { return __builtin_amdgcn_rcpf(x); }
__device__ __forceinline__ float silu_f(float v)   { return v * fast_rcp(1.0f + __expf(-v)); }

// ---------------- Pre-kernel: tabulate scale_ee * MLP_ee(r) on [0,16) ----------------
__global__ void build_ee_table(const float* __restrict__ W1, const float* __restrict__ b1,
                               const float* __restrict__ W2, const float* __restrict__ b2,
                               const float* __restrict__ W3, const float* __restrict__ b3,
                               const float* __restrict__ scale_ee,
                               const float* __restrict__ b_en, const float* __restrict__ b_ee,
                               float* __restrict__ table, float* __restrict__ aux)
{
    const int tid   = threadIdx.x;
    if (blockIdx.x == 0) {
        if (tid < N_NUC) aux[tid] = __logf(1.0f + __expf(b_en[tid]));
        if (tid == N_NUC) aux[tid] = __logf(1.0f + __expf(b_ee[0]));
    }
    const int j     = tid & 31;                    // hidden unit (layer 2)
    const int entry = blockIdx.x * 8 + (tid >> 5); // table index
    const float r   = (float)entry * TAB_H;

    float g = b2[j];
#pragma unroll
    for (int k = 0; k < D_H; ++k) {
        float hk = silu_f(r * W1[k] + b1[k]);      // layer 1 (input dim = 1)
        g += hk * W2[k * D_H + j];
    }
    float o = silu_f(g) * W3[j];
#pragma unroll
    for (int m = 16; m; m >>= 1) o += __shfl_xor(o, m, 32);
    if (j == 0) table[entry] = scale_ee[0] * (o + b3[0]);
}

// ---------------- Main kernel ----------------
// 256 threads = 4 waves = 2 wave-pairs. Each pair handles 2 walkers (lanes 0-31 /
// 32-63); the two waves of a pair are copies c=0/1 splitting the per-electron work:
//   copy c: layer-2 columns [16c,16c+16), e-e d in [1+8c, 8+8c], cusp nuclei [4c,4c+4).
// Layer 1 duplicated (cheap). Copy index forced to SGPR via readfirstlane so all
// weight accesses stay wave-uniform scalar loads. 8192 waves -> ~7-8 waves/SIMD.
__launch_bounds__(256, 7)
__global__ void jastrow_kernel(const float* __restrict__ re, const float* __restrict__ rnuc,
                               const float* __restrict__ charges, const int* __restrict__ mask,
                               const float* __restrict__ W1, const float* __restrict__ b1,
                               const float* __restrict__ W2, const float* __restrict__ b2,
                               const float* __restrict__ W3, const float* __restrict__ b3,
                               const float* __restrict__ scale_en, const float* __restrict__ table,
                               const float* __restrict__ aux,
                               float* __restrict__ out)
{
    __shared__ __align__(16) float sTab[NTAB];     // 16 KB
    __shared__ float4 sC4[WPB][N_E];               // 2 KB
    __shared__ float  sA2[16][N_E];                // 2 KB
    __shared__ float  sRed[WPB][2];

    const int tid = threadIdx.x;

    {   // stage ee table (vectorized, 4 float4 per thread)
        const float4* tg = (const float4*)table;
        float4* ts = (float4*)sTab;
        ts[tid]       = tg[tid];
        ts[tid + 256] = tg[tid + 256];
        ts[tid + 512] = tg[tid + 512];
        ts[tid + 768] = tg[tid + 768];
    }
    // rotation-pair a-coefficients: 512 entries, 2 per thread
#pragma unroll
    for (int q = 0; q < 2; ++q) {
        int idx = tid + q * 256;
        int d = (idx >> 5) + 1, l0 = idx & 31;
        int jn = (l0 + d) & 31;
        int a = l0 < jn ? l0 : jn, b = l0 < jn ? jn : l0;
        sA2[d - 1][l0] = mask[a * N_E + b] ? 0.25f : 0.5f;
    }

    const int wave = tid >> 6;
    const int p    = wave >> 1;                    // wave-pair index (0..1)
    const int cu   = __builtin_amdgcn_readfirstlane(wave & 1);  // copy, forced SGPR
    const int s    = (tid >> 5) & 1;               // walker-within-pair
    const int e    = tid & 31;                     // electron index
    const int Wl   = (p << 1) | s;                 // walker slot in block (0..3)
    const int gw   = blockIdx.x * WPB + Wl;

    const float* rp = re + ((size_t)gw * N_E + e) * 3;
    float ex = rp[0], ey = rp[1], ez = rp[2];
    if (cu == 0) sC4[Wl][e] = make_float4(ex, ey, ez, 0.0f);
    __syncthreads();

    float acc = 0.0f;

    // ---- r^2 to all 8 nuclei (needed fully by layer 1 in both copies) ----
    float x[N_NUC];
#pragma unroll
    for (int n = 0; n < N_NUC; ++n) {
        float dx = ex - rnuc[n * 3 + 0];
        float dy = ey - rnuc[n * 3 + 1];
        float dz = ez - rnuc[n * 3 + 2];
        x[n] = dx * dx + dy * dy + dz * dz;
    }
    // ---- cusp: 4 nuclei per copy (literal indices; uniform branch) ----
    if (cu == 0) {
#pragma unroll
        for (int n = 0; n < 4; ++n) {
            float r = sqrtf(x[n]);
            acc -= charges[n] * r * fast_rcp(1.0f + aux[n] * r);
        }
    } else {
#pragma unroll
        for (int n = 4; n < 8; ++n) {
            float r = sqrtf(x[n]);
            acc -= charges[n] * r * fast_rcp(1.0f + aux[n] * r);
        }
    }

    // ---- e-n MLP layer 1: 8 -> 32, duplicated in both copies, packed fp32 ----
    float2 hh[D_H / 2];
#pragma unroll
    for (int j = 0; j < D_H / 2; ++j) hh[j] = ((const float2*)b1)[j];
#pragma unroll
    for (int k = 0; k < N_NUC; ++k) {
        float xk = x[k];
        const float2* row = (const float2*)(W1 + k * D_H);
#pragma unroll
        for (int j = 0; j < D_H / 2; ++j) {
            float2 wv = row[j];
            hh[j].x = fmaf(xk, wv.x, hh[j].x);
            hh[j].y = fmaf(xk, wv.y, hh[j].y);
        }
    }
#pragma unroll
    for (int j = 0; j < D_H / 2; ++j) { hh[j].x = silu_f(hh[j].x); hh[j].y = silu_f(hh[j].y); }

    // ---- layer 2: this copy's 16 columns [16cu, 16cu+16), packed fp32 ----
    float2 g2[8];
#pragma unroll
    for (int j = 0; j < 8; ++j) g2[j] = ((const float2*)(b2 + cu * 16))[j];
#pragma unroll
    for (int k = 0; k < D_H; ++k) {
        float hk = (k & 1) ? hh[k >> 1].y : hh[k >> 1].x;   // literal k -> register
        const float2* row = (const float2*)(W2 + k * D_H + cu * 16);
#pragma unroll
        for (int j = 0; j < 8; ++j) {
            float2 wv = row[j];
            g2[j].x = fmaf(hk, wv.x, g2[j].x);
            g2[j].y = fmaf(hk, wv.y, g2[j].y);
        }
    }
    float o = (cu == 0) ? b3[0] : 0.0f;            // b3 added once per electron
#pragma unroll
    for (int j = 0; j < 8; ++j) {
        o += silu_f(g2[j].x) * W3[cu * 16 + 2 * j + 0];
        o += silu_f(g2[j].y) * W3[cu * 16 + 2 * j + 1];
    }
    acc += scale_en[0] * o;

    // ---- e-e: 8 rotation distances per copy ----
    float bs = aux[N_NUC];                         // softplus(b_ee)
#pragma unroll
    for (int dd = 0; dd < 8; ++dd) {
        int d = cu * 8 + dd + 1;                   // copy0: 1..8, copy1: 9..16
        int jn = (e + d) & 31;
        float4 cj = sC4[Wl][jn];
        float dx = ex - cj.x, dy = ey - cj.y, dz = ez - cj.z;
        float r = sqrtf(dx * dx + dy * dy + dz * dz);
        float ct = sA2[d - 1][e] * r * fast_rcp(1.0f + bs * r);
        float t = r * TAB_INVH;
        int i0 = (int)t;
        if (i0 > NTAB - 2) i0 = NTAB - 2;
        float f = t - (float)i0;
        float t0 = sTab[i0], t1 = sTab[i0 + 1];
        float contrib = ct + t0 + f * (t1 - t0);
        acc += (d == 16) ? 0.5f * contrib : contrib;   // d=16 pairs counted twice
    }

    // ---- reduce 32 lanes (one walker, one copy) ----
#pragma unroll
    for (int m = 16; m; m >>= 1) acc += __shfl_xor(acc, m, 32);
    if (e == 0) sRed[Wl][cu] = acc;
    __syncthreads();
    if (tid < WPB) out[blockIdx.x * WPB + tid] = sRed[tid][0] + sRed[tid][1];
}

extern "C" void kernel_launch(void* const* d_in, const int* in_sizes, int n_in,
                              void* d_out, int out_size, void* d_ws, size_t ws_size,
                              hipStream_t stream)
{
    const float* re       = (const float*)d_in[0];
    const float* rnuc     = (const float*)d_in[1];
    const float* charges  = (const float*)d_in[2];
    const int*   mask     = (const int*)d_in[3];
    const float* b_en     = (const float*)d_in[4];
    const float* b_ee     = (const float*)d_in[5];
    const float* W1_en    = (const float*)d_in[6];
    const float* b1_en    = (const float*)d_in[7];
    const float* W2_en    = (const float*)d_in[8];
    const float* b2_en    = (const float*)d_in[9];
    const float* W3_en    = (const float*)d_in[10];
    const float* b3_en    = (const float*)d_in[11];
    const float* W1_ee    = (const float*)d_in[12];
    const float* b1_ee    = (const float*)d_in[13];
    const float* W2_ee    = (const float*)d_in[14];
    const float* b2_ee    = (const float*)d_in[15];
    const float* W3_ee    = (const float*)d_in[16];
    const float* b3_ee    = (const float*)d_in[17];
    const float* scale_en = (const float*)d_in[18];
    const float* scale_ee = (const float*)d_in[19];

    float* out   = (float*)d_out;
    float* table = (float*)d_ws;          // NTAB floats = 16 KB
    float* aux   = table + NTAB;          // softplus(b_en[0..7]), softplus(b_ee)

    build_ee_table<<<NTAB / 8, 256, 0, stream>>>(W1_ee, b1_ee, W2_ee, b2_ee,
                                                 W3_ee, b3_ee, scale_ee,
                                                 b_en, b_ee, table, aux);
    jastrow_kernel<<<N_W / WPB, 256, 0, stream>>>(re, rnuc, charges, mask,
                                                  W1_en, b1_en, W2_en, b2_en, W3_en, b3_en,
                                                  scale_en, table, aux, out);
}

// Round 5
// 30.511 us; speedup vs baseline: 1.8304x; 1.8304x over previous
//
#include <hip/hip_runtime.h>

#define N_W   8192
#define N_E   32
#define N_NUC 8
#define D_H   32
#define NTAB  4096
#define TAB_INVH 256.0f    // table step = 1/256, range [0, 16)
#define TAB_H    (1.0f/256.0f)
#define WPB   8            // walkers per block (256 threads, 1 thread = 1 electron)

__device__ __forceinline__ float fast_rcp(float x) { return __builtin_amdgcn_rcpf(x); }
__device__ __forceinline__ float silu_f(float v)   { return v * fast_rcp(1.0f + __expf(-v)); }

// ---------------- Pre-kernel: tabulate scale_ee * MLP_ee(r) on [0,16) ----------------
// One table entry per 32-lane group; lane j owns hidden unit j of layer 2.
// Block 0 additionally writes softplus(b_en[0..7]), softplus(b_ee), and the
// prescaled pair coefficients aA[16][32] (0.25/0.5, with the d=16 x0.5 folded).
__global__ void build_ee_table(const float* __restrict__ W1, const float* __restrict__ b1,
                               const float* __restrict__ W2, const float* __restrict__ b2,
                               const float* __restrict__ W3, const float* __restrict__ b3,
                               const float* __restrict__ scale_ee,
                               const float* __restrict__ b_en, const float* __restrict__ b_ee,
                               const int* __restrict__ mask,
                               float* __restrict__ table, float* __restrict__ aux,
                               float* __restrict__ aA)
{
    const int tid = threadIdx.x;
    if (blockIdx.x == 0) {
        if (tid < N_NUC) aux[tid] = __logf(1.0f + __expf(b_en[tid]));
        if (tid == N_NUC) aux[tid] = __logf(1.0f + __expf(b_ee[0]));
        // pair coefficients: pair (l, (l+d)&31), d in 1..16
#pragma unroll
        for (int q = 0; q < 2; ++q) {
            int idx = tid + q * 256;              // 512 entries
            int d = (idx >> 5) + 1, l0 = idx & 31;
            int jn = (l0 + d) & 31;
            int a = l0 < jn ? l0 : jn, b = l0 < jn ? jn : l0;
            float av = mask[a * N_E + b] ? 0.25f : 0.5f;
            if (d == 16) av *= 0.5f;              // d=16 pairs counted twice
            aA[(d - 1) * N_E + l0] = av;
        }
    }
    const int j     = tid & 31;                    // hidden unit (layer 2)
    const int entry = blockIdx.x * 8 + (tid >> 5); // table index
    const float r   = (float)entry * TAB_H;

    float g = b2[j];
#pragma unroll
    for (int k = 0; k < D_H; ++k) {
        float hk = silu_f(r * W1[k] + b1[k]);      // layer 1 (input dim = 1)
        g += hk * W2[k * D_H + j];
    }
    float o = silu_f(g) * W3[j];
#pragma unroll
    for (int m = 16; m; m >>= 1) o += __shfl_xor(o, m, 32);
    if (j == 0) table[entry] = scale_ee[0] * (o + b3[0]);
}

// ---------------- Main kernel: barrier-free, LDS-free ----------------
// 1 thread = 1 electron, 8 walkers/block. Weights/nuclei via wave-uniform scalar
// loads (K$); partner coords re-read from global (same 384B row -> L1 hits);
// ee table + pair coefs gathered from global (16KB + 2KB, L1/L2-resident).
// No __shared__, no __syncthreads: waves are fully independent -> no barrier
// convoy, no vmcnt(0) drain, no LDS bank conflicts.
__launch_bounds__(256, 4)
__global__ void jastrow_kernel(const float* __restrict__ re, const float* __restrict__ rnuc,
                               const float* __restrict__ charges,
                               const float* __restrict__ W1, const float* __restrict__ b1,
                               const float* __restrict__ W2, const float* __restrict__ b2,
                               const float* __restrict__ W3, const float* __restrict__ b3,
                               const float* __restrict__ scale_en,
                               const float* __restrict__ table, const float* __restrict__ aux,
                               const float* __restrict__ aA,
                               float* __restrict__ out)
{
    const int tid = threadIdx.x;
    const int v = tid >> 5;       // walker slot in block
    const int e = tid & 31;       // electron index
    const int w = blockIdx.x * WPB + v;

    const float* cbase = re + (size_t)w * (N_E * 3);
    float ex = cbase[e * 3 + 0], ey = cbase[e * 3 + 1], ez = cbase[e * 3 + 2];

    float acc = 0.0f;

    // ---- e-n: cusp + squared distances (softplus(b_en) precomputed in aux) ----
    float x[N_NUC];
#pragma unroll
    for (int n = 0; n < N_NUC; ++n) {
        float dx = ex - rnuc[n * 3 + 0];
        float dy = ey - rnuc[n * 3 + 1];
        float dz = ez - rnuc[n * 3 + 2];
        float r2 = dx * dx + dy * dy + dz * dz;
        x[n] = r2;
        float r = sqrtf(r2);
        acc -= charges[n] * r * fast_rcp(1.0f + aux[n] * r);
    }

    // ---- e-e: rotation enumeration, partner coords from L1, table from L1/L2 ----
    float bs = aux[N_NUC];                         // softplus(b_ee)
#pragma unroll
    for (int d = 1; d <= 16; ++d) {
        int jn = (e + d) & 31;
        float cjx = cbase[jn * 3 + 0];
        float cjy = cbase[jn * 3 + 1];
        float cjz = cbase[jn * 3 + 2];
        float dx = ex - cjx, dy = ey - cjy, dz = ez - cjz;
        float r = sqrtf(dx * dx + dy * dy + dz * dz);
        float ct = aA[(d - 1) * N_E + e] * r * fast_rcp(1.0f + bs * r);
        float t = r * TAB_INVH;
        int i0 = (int)t;
        if (i0 > NTAB - 2) i0 = NTAB - 2;
        float f = t - (float)i0;
        float t0 = table[i0], t1 = table[i0 + 1];
        float tv = t0 + f * (t1 - t0);
        acc += ct + ((d == 16) ? 0.5f * tv : tv);
    }

    // ---- e-n MLP layer 1: 8 -> 32, packed fp32, weights via K$ ----
    float2 hh[D_H / 2];
#pragma unroll
    for (int j = 0; j < D_H / 2; ++j) hh[j] = ((const float2*)b1)[j];
#pragma unroll
    for (int k = 0; k < N_NUC; ++k) {
        float xk = x[k];
        const float2* row = (const float2*)(W1 + k * D_H);
#pragma unroll
        for (int j = 0; j < D_H / 2; ++j) {
            float2 wv = row[j];
            hh[j].x = fmaf(xk, wv.x, hh[j].x);
            hh[j].y = fmaf(xk, wv.y, hh[j].y);
        }
    }
    float h[D_H];
#pragma unroll
    for (int j = 0; j < D_H / 2; ++j) {
        h[2 * j + 0] = silu_f(hh[j].x);
        h[2 * j + 1] = silu_f(hh[j].y);
    }

    // ---- layer 2: 32 -> 32 in two 16-wide halves (caps VGPR), packed fp32 ----
    float o = b3[0];
#pragma unroll
    for (int half = 0; half < 2; ++half) {
        float2 g2[8];
#pragma unroll
        for (int j = 0; j < 8; ++j) g2[j] = ((const float2*)b2)[half * 8 + j];
#pragma unroll
        for (int k = 0; k < D_H; ++k) {
            float hk = h[k];
            const float2* row = (const float2*)(W2 + k * D_H + half * 16);
#pragma unroll
            for (int j = 0; j < 8; ++j) {
                float2 wv = row[j];
                g2[j].x = fmaf(hk, wv.x, g2[j].x);
                g2[j].y = fmaf(hk, wv.y, g2[j].y);
            }
        }
#pragma unroll
        for (int j = 0; j < 8; ++j) {
            o += silu_f(g2[j].x) * W3[half * 16 + 2 * j + 0];
            o += silu_f(g2[j].y) * W3[half * 16 + 2 * j + 1];
        }
    }
    acc += scale_en[0] * o;

    // ---- reduce 32 lanes (one walker) ----
#pragma unroll
    for (int m = 16; m; m >>= 1) acc += __shfl_xor(acc, m, 32);
    if (e == 0) out[w] = acc;
}

extern "C" void kernel_launch(void* const* d_in, const int* in_sizes, int n_in,
                              void* d_out, int out_size, void* d_ws, size_t ws_size,
                              hipStream_t stream)
{
    const float* re       = (const float*)d_in[0];
    const float* rnuc     = (const float*)d_in[1];
    const float* charges  = (const float*)d_in[2];
    const int*   mask     = (const int*)d_in[3];
    const float* b_en     = (const float*)d_in[4];
    const float* b_ee     = (const float*)d_in[5];
    const float* W1_en    = (const float*)d_in[6];
    const float* b1_en    = (const float*)d_in[7];
    const float* W2_en    = (const float*)d_in[8];
    const float* b2_en    = (const float*)d_in[9];
    const float* W3_en    = (const float*)d_in[10];
    const float* b3_en    = (const float*)d_in[11];
    const float* W1_ee    = (const float*)d_in[12];
    const float* b1_ee    = (const float*)d_in[13];
    const float* W2_ee    = (const float*)d_in[14];
    const float* b2_ee    = (const float*)d_in[15];
    const float* W3_ee    = (const float*)d_in[16];
    const float* b3_ee    = (const float*)d_in[17];
    const float* scale_en = (const float*)d_in[18];
    const float* scale_ee = (const float*)d_in[19];

    float* out   = (float*)d_out;
    float* table = (float*)d_ws;          // NTAB floats = 16 KB
    float* aux   = table + NTAB;          // softplus(b_en[0..7]), softplus(b_ee)
    float* aA    = aux + 16;              // 16 x 32 prescaled pair coefficients

    build_ee_table<<<NTAB / 8, 256, 0, stream>>>(W1_ee, b1_ee, W2_ee, b2_ee,
                                                 W3_ee, b3_ee, scale_ee,
                                                 b_en, b_ee, mask, table, aux, aA);
    jastrow_kernel<<<N_W / WPB, 256, 0, stream>>>(re, rnuc, charges,
                                                  W1_en, b1_en, W2_en, b2_en, W3_en, b3_en,
                                                  scale_en, table, aux, aA, out);
}

// Round 6
// 23.485 us; speedup vs baseline: 2.3779x; 1.2992x over previous
//
#include <hip/hip_runtime.h>

#define N_W   8192
#define N_E   32
#define N_NUC 8
#define D_H   32
#define NTAB  4096
#define TAB_INVH 256.0f    // table step = 1/256, range [0, 16)
#define TAB_H    (1.0f/256.0f)
#define WPB   8            // walkers per block; wave = 2 walkers (lanes 0-31 / 32-63)

// ws layout (float units): [0,4096) ee-table | [4096,4112) aux | [4112,4624) aT[32][16]
// | [4624,4656) W3*scale_en | [4656, +512 u32) W2 bf16 B-fragments
#define AUX_OFF 4096
#define AT_OFF  4112
#define W3S_OFF 4624
#define B_OFF   4656
// aux: [0..7] softplus(b_en), [8] softplus(b_ee), [9] 32*scale_en*b3_en

typedef __attribute__((ext_vector_type(8)))  short bf16x8_t;   // 8 bf16 = 4 VGPR
typedef __attribute__((ext_vector_type(16))) float f32x16_t;   // MFMA accumulator

union FragAB { bf16x8_t s; unsigned u[4]; };

__device__ __forceinline__ float fast_rcp(float x) { return __builtin_amdgcn_rcpf(x); }
__device__ __forceinline__ float silu_f(float v)   { return v * fast_rcp(1.0f + __expf(-v)); }
__device__ __forceinline__ unsigned pk_bf16(float lo, float hi) {
    unsigned r;
    asm("v_cvt_pk_bf16_f32 %0, %1, %2" : "=v"(r) : "v"(lo), "v"(hi));
    return r;
}

// ---------------- Pre-kernel: ee table + aux + pair coefs + W2 bf16 fragments ----------------
__global__ void build_tables(const float* __restrict__ W1ee, const float* __restrict__ b1ee,
                             const float* __restrict__ W2ee, const float* __restrict__ b2ee,
                             const float* __restrict__ W3ee, const float* __restrict__ b3ee,
                             const float* __restrict__ scale_ee,
                             const float* __restrict__ b_en, const float* __restrict__ b_ee,
                             const int* __restrict__ mask,
                             const float* __restrict__ W2en, const float* __restrict__ W3en,
                             const float* __restrict__ b3en, const float* __restrict__ scale_en,
                             float* __restrict__ ws)
{
    const int tid = threadIdx.x;
    if (blockIdx.x == 0) {
        float* aux = ws + AUX_OFF;
        if (tid < N_NUC) aux[tid] = __logf(1.0f + __expf(b_en[tid]));
        if (tid == 8)    aux[8]   = __logf(1.0f + __expf(b_ee[0]));
        if (tid == 9)    aux[9]   = 32.0f * scale_en[0] * b3en[0];
        if (tid < D_H)   ws[W3S_OFF + tid] = W3en[tid] * scale_en[0];
        // aT[e][d-1]: pair (e,(e+d)&31) coef 0.25/0.5, d=16 pre-halved (counted twice)
        float* aT = ws + AT_OFF;
#pragma unroll
        for (int q = 0; q < 2; ++q) {
            int idx = tid + q * 256;               // 512 entries
            int e = idx >> 4, dm = idx & 15, d = dm + 1;
            int jn = (e + d) & 31;
            int a = e < jn ? e : jn, b = e < jn ? jn : e;
            float av = mask[a * N_E + b] ? 0.25f : 0.5f;
            if (d == 16) av *= 0.5f;
            aT[e * 16 + dm] = av;
        }
        // W2_en -> bf16 B-fragments: lane l, slot s (m=s>>2, r=s&3):
        //   k = m*16 + (l>>5)*8 + 2r, j = l&31; packed (lo=k, hi=k+1)
        unsigned* wsB = (unsigned*)(ws + B_OFF);
#pragma unroll
        for (int q = 0; q < 2; ++q) {
            int idx = tid + q * 256;               // 512 = 64 lanes x 8 slots
            int lane = idx >> 3, slot = idx & 7;
            int m = slot >> 2, r = slot & 3;
            int k = m * 16 + ((lane >> 5) << 3) + (r << 1);
            int j = lane & 31;
            wsB[lane * 8 + slot] = pk_bf16(W2en[k * D_H + j], W2en[(k + 1) * D_H + j]);
        }
    }
    // ee table: one entry per 32-lane group, lane j = hidden unit
    const int j     = tid & 31;
    const int entry = blockIdx.x * 8 + (tid >> 5);
    const float r   = (float)entry * TAB_H;
    float g = b2ee[j];
#pragma unroll
    for (int k = 0; k < D_H; ++k) g += silu_f(r * W1ee[k] + b1ee[k]) * W2ee[k * D_H + j];
    float o = silu_f(g) * W3ee[j];
#pragma unroll
    for (int m = 16; m; m >>= 1) o += __shfl_xor(o, m, 32);
    if (j == 0) ws[entry] = scale_ee[0] * (o + b3ee[0]);
}

// ---------------- Main kernel ----------------
// 1 thread = 1 electron; wave = 2 walkers. Layer-2 (32x32) via 2x2 MFMA
// v_mfma_f32_32x32x16_bf16 per wave; W2 arrives as pre-packed B-fragments
// (2 dwordx4 vector loads — replaces the 1024-float s_load stream, the
// suspected stall source). A-fragments: cvt_pk_bf16 + 16 shfl_xor(.,32).
// Layout-permutation-safe: A and B share the k-packing; rows sum out.
__launch_bounds__(256, 4)
__global__ void jastrow_kernel(const float* __restrict__ re, const float* __restrict__ rnuc,
                               const float* __restrict__ charges,
                               const float* __restrict__ W1, const float* __restrict__ b1,
                               const float* __restrict__ b2,
                               const float* __restrict__ ws,
                               float* __restrict__ out)
{
    const int tid  = threadIdx.x;
    const int e    = tid & 31;          // electron
    const int half = (tid >> 5) & 1;    // 0: walker A of wave, 1: walker B
    const int v    = tid >> 5;          // walker slot in block (0..7)
    const int w    = blockIdx.x * WPB + v;
    const float* aux = ws + AUX_OFF;

    const float* cb = re + ((size_t)w * N_E + e) * 3;
    float ex = cb[0], ey = cb[1], ez = cb[2];

    float acc = 0.0f;

    // ---- e-n cusp + r^2 ----
    float x[N_NUC];
#pragma unroll
    for (int n = 0; n < N_NUC; ++n) {
        float dx = ex - rnuc[n * 3 + 0];
        float dy = ey - rnuc[n * 3 + 1];
        float dz = ez - rnuc[n * 3 + 2];
        float r2 = dx * dx + dy * dy + dz * dz;
        x[n] = r2;
        float r = sqrtf(r2);
        acc -= charges[n] * r * fast_rcp(1.0f + aux[n] * r);
    }

    // ---- layer 1: 8 -> 32, fp32 packed, weights via K$ (only 256 floats) ----
    float2 hh[D_H / 2];
#pragma unroll
    for (int j = 0; j < D_H / 2; ++j) hh[j] = ((const float2*)b1)[j];
#pragma unroll
    for (int k = 0; k < N_NUC; ++k) {
        float xk = x[k];
        const float2* row = (const float2*)(W1 + k * D_H);
#pragma unroll
        for (int j = 0; j < D_H / 2; ++j) {
            float2 wv = row[j];
            hh[j].x = fmaf(xk, wv.x, hh[j].x);
            hh[j].y = fmaf(xk, wv.y, hh[j].y);
        }
    }
    // silu + pack to bf16 pairs: hpk[i] = (h[2i] lo, h[2i+1] hi), k-major
    unsigned hpk[16];
#pragma unroll
    for (int i = 0; i < 16; ++i) hpk[i] = pk_bf16(silu_f(hh[i].x), silu_f(hh[i].y));
    // cross-half exchange: lane l <-> l^32
    unsigned sx[16];
#pragma unroll
    for (int i = 0; i < 16; ++i) sx[i] = (unsigned)__shfl_xor((int)hpk[i], 32, 64);

    // B fragments (wave-shared W2, pre-packed)
    FragAB B1, B2;
    {
        const unsigned* wsB = (const unsigned*)(ws + B_OFF) + (size_t)(tid & 63) * 8;
        uint4 q0 = *(const uint4*)wsB;
        uint4 q1 = *(const uint4*)(wsB + 4);
        B1.u[0] = q0.x; B1.u[1] = q0.y; B1.u[2] = q0.z; B1.u[3] = q0.w;
        B2.u[0] = q1.x; B2.u[1] = q1.y; B2.u[2] = q1.z; B2.u[3] = q1.w;
    }
    // A fragments: lane l supplies row (l&31), k-half (l>>5)*8
    const bool lo = (tid & 32) == 0;
    FragAB A1a, A2a, A1b, A2b;
#pragma unroll
    for (int r = 0; r < 4; ++r) {
        A1a.u[r] = lo ? hpk[r]      : sx[4 + r];    // walker A, k 0..15
        A2a.u[r] = lo ? hpk[8 + r]  : sx[12 + r];   // walker A, k 16..31
        A1b.u[r] = lo ? sx[r]       : hpk[4 + r];   // walker B, k 0..15
        A2b.u[r] = lo ? sx[8 + r]   : hpk[12 + r];  // walker B, k 16..31
    }
    float vb2 = b2[e];                              // C init = bias (col j = lane&31)
    f32x16_t accA, accB;
#pragma unroll
    for (int r = 0; r < 16; ++r) { accA[r] = vb2; accB[r] = vb2; }
    accA = __builtin_amdgcn_mfma_f32_32x32x16_bf16(A1a.s, B1.s, accA, 0, 0, 0);
    accA = __builtin_amdgcn_mfma_f32_32x32x16_bf16(A2a.s, B2.s, accA, 0, 0, 0);
    accB = __builtin_amdgcn_mfma_f32_32x32x16_bf16(A1b.s, B1.s, accB, 0, 0, 0);
    accB = __builtin_amdgcn_mfma_f32_32x32x16_bf16(A2b.s, B2.s, accB, 0, 0, 0);

    // epilogue: sum silu over rows (electrons), weight by W3*scale (col j = lane&31)
    float w3s = ws[W3S_OFF + e];
    float sA = 0.0f, sB = 0.0f;
#pragma unroll
    for (int r = 0; r < 16; ++r) { sA += silu_f(accA[r]); sB += silu_f(accB[r]); }
    float mlpA = sA * w3s, mlpB = sB * w3s;

    // ---- e-e: rotation pairs, partners via shfl, coefs via 16B vector loads ----
    float bs = aux[8];
    float av[16];
    {
        const float* aT = ws + AT_OFF + e * 16;
#pragma unroll
        for (int i = 0; i < 16; ++i) av[i] = aT[i];
    }
#pragma unroll
    for (int d = 1; d <= 16; ++d) {
        int jn = (e + d) & 31;
        float cjx = __shfl(ex, jn, 32);
        float cjy = __shfl(ey, jn, 32);
        float cjz = __shfl(ez, jn, 32);
        float dx = ex - cjx, dy = ey - cjy, dz = ez - cjz;
        float r = sqrtf(dx * dx + dy * dy + dz * dz);
        float ct = av[d - 1] * r * fast_rcp(1.0f + bs * r);
        float t = r * TAB_INVH;
        int i0 = (int)t;
        if (i0 > NTAB - 2) i0 = NTAB - 2;
        float f = t - (float)i0;
        const float* tp = ws + i0;
        float tv = tp[0] + f * (tp[1] - tp[0]);
        acc += ct + ((d == 16) ? 0.5f * tv : tv);
    }

    // ---- per-walker totals: MLP part spans all 64 lanes, ee/cusp per 32-half ----
    float valA = mlpA + (half ? 0.0f : acc);
    float valB = mlpB + (half ? acc : 0.0f);
#pragma unroll
    for (int m = 32; m; m >>= 1) {
        valA += __shfl_xor(valA, m, 64);
        valB += __shfl_xor(valB, m, 64);
    }
    if ((tid & 63) == 0) {
        int wA = blockIdx.x * WPB + ((tid >> 6) << 1);
        out[wA]     = valA + aux[9];
        out[wA + 1] = valB + aux[9];
    }
}

extern "C" void kernel_launch(void* const* d_in, const int* in_sizes, int n_in,
                              void* d_out, int out_size, void* d_ws, size_t ws_size,
                              hipStream_t stream)
{
    const float* re       = (const float*)d_in[0];
    const float* rnuc     = (const float*)d_in[1];
    const float* charges  = (const float*)d_in[2];
    const int*   mask     = (const int*)d_in[3];
    const float* b_en     = (const float*)d_in[4];
    const float* b_ee     = (const float*)d_in[5];
    const float* W1_en    = (const float*)d_in[6];
    const float* b1_en    = (const float*)d_in[7];
    const float* W2_en    = (const float*)d_in[8];
    const float* b2_en    = (const float*)d_in[9];
    const float* W3_en    = (const float*)d_in[10];
    const float* b3_en    = (const float*)d_in[11];
    const float* W1_ee    = (const float*)d_in[12];
    const float* b1_ee    = (const float*)d_in[13];
    const float* W2_ee    = (const float*)d_in[14];
    const float* b2_ee    = (const float*)d_in[15];
    const float* W3_ee    = (const float*)d_in[16];
    const float* b3_ee    = (const float*)d_in[17];
    const float* scale_en = (const float*)d_in[18];
    const float* scale_ee = (const float*)d_in[19];

    float* out = (float*)d_out;
    float* ws  = (float*)d_ws;

    build_tables<<<NTAB / 8, 256, 0, stream>>>(W1_ee, b1_ee, W2_ee, b2_ee, W3_ee, b3_ee,
                                               scale_ee, b_en, b_ee, mask,
                                               W2_en, W3_en, b3_en, scale_en, ws);
    jastrow_kernel<<<N_W / WPB, 256, 0, stream>>>(re, rnuc, charges,
                                                  W1_en, b1_en, b2_en, ws, out);
}